// Round 1
// baseline (151.629 us; speedup 1.0000x reference)
//
#include <hip/hip_runtime.h>
#include <hip/hip_bf16.h>

#define CIN  32
#define COUT 64
#define KVOL 27
#define KCEN 13
#define FEPS 1e-5f

// ws float layout:
// [0,32)    channel sums
// [32,64)   channel sums of squares
// [64,96)   scale[c] = gamma*rsqrt(var+eps)
// [96,128)  bias[c]  = beta - mean*scale
// [128,...) xhat[N][32]  (normalized+ReLU features)

__global__ void k_zero(float* __restrict__ ws) {
    ws[threadIdx.x] = 0.f;   // 128 threads zero the header
}

// Grid-stride float4 reduction. Each thread's float4 index q keeps q%8 constant
// (stride is a multiple of 8), so it owns a fixed channel group g = 4*(q%8)..+3.
__global__ __launch_bounds__(256) void k_reduce(const float* __restrict__ f,
                                                float* __restrict__ ws, int n4) {
    const float4* f4 = (const float4*)f;
    int tid    = blockIdx.x * blockDim.x + threadIdx.x;
    int stride = gridDim.x * blockDim.x;          // multiple of 8
    float4 s = make_float4(0.f, 0.f, 0.f, 0.f);
    float4 q = make_float4(0.f, 0.f, 0.f, 0.f);
    for (int i = tid; i < n4; i += stride) {
        float4 v = f4[i];
        s.x += v.x; s.y += v.y; s.z += v.z; s.w += v.w;
        q.x = fmaf(v.x, v.x, q.x); q.y = fmaf(v.y, v.y, q.y);
        q.z = fmaf(v.z, v.z, q.z); q.w = fmaf(v.w, v.w, q.w);
    }
    __shared__ float ls[64];
    if (threadIdx.x < 64) ls[threadIdx.x] = 0.f;
    __syncthreads();
    int g = threadIdx.x & 7;                      // == tid & 7
    atomicAdd(&ls[g * 4 + 0], s.x); atomicAdd(&ls[g * 4 + 1], s.y);
    atomicAdd(&ls[g * 4 + 2], s.z); atomicAdd(&ls[g * 4 + 3], s.w);
    atomicAdd(&ls[32 + g * 4 + 0], q.x); atomicAdd(&ls[32 + g * 4 + 1], q.y);
    atomicAdd(&ls[32 + g * 4 + 2], q.z); atomicAdd(&ls[32 + g * 4 + 3], q.w);
    __syncthreads();
    if (threadIdx.x < 64) atomicAdd(&ws[threadIdx.x], ls[threadIdx.x]);
}

__global__ void k_final(const float* __restrict__ gamma, const float* __restrict__ beta,
                        float* __restrict__ ws, float invN) {
    int c = threadIdx.x;                          // 32 threads
    float mean = ws[c] * invN;
    float var  = fmaf(-mean, mean, ws[32 + c] * invN);
    float sc   = gamma[c] * rsqrtf(var + FEPS);
    ws[64 + c] = sc;
    ws[96 + c] = fmaf(-mean, sc, beta[c]);
}

// xhat = relu(f*scale + bias), vectorized float4 (channel group fixed per thread).
__global__ __launch_bounds__(256) void k_norm(const float* __restrict__ f,
                                              const float* __restrict__ ws,
                                              float* __restrict__ xhat, int n4) {
    const float4* f4 = (const float4*)f;
    float4* o4 = (float4*)xhat;
    int tid    = blockIdx.x * blockDim.x + threadIdx.x;
    int stride = gridDim.x * blockDim.x;          // multiple of 8
    int g = threadIdx.x & 7;
    float4 sc = ((const float4*)(ws + 64))[g];
    float4 bi = ((const float4*)(ws + 96))[g];
    for (int i = tid; i < n4; i += stride) {
        float4 v = f4[i];
        v.x = fmaxf(fmaf(v.x, sc.x, bi.x), 0.f);
        v.y = fmaxf(fmaf(v.y, sc.y, bi.y), 0.f);
        v.z = fmaxf(fmaf(v.z, sc.z, bi.z), 0.f);
        v.w = fmaxf(fmaf(v.w, sc.w, bi.w), 0.f);
        o4[i] = v;
    }
}

// Dense center pass (k=13: neighbor == self, always valid).
// Wave-per-voxel-stream: lane = output channel, W[13] column held in 32 VGPRs.
// Plain stores double as the zero-init of out.
__global__ __launch_bounds__(256) void k_center(const float* __restrict__ xhat,
                                                const float* __restrict__ W,
                                                float* __restrict__ out, int n) {
    int lane = threadIdx.x;                       // 0..63
    float w[CIN];
#pragma unroll
    for (int c = 0; c < CIN; ++c) w[c] = W[KCEN * (CIN * COUT) + c * COUT + lane];

    int wid = __builtin_amdgcn_readfirstlane(blockIdx.x * 4 + threadIdx.y);
    int waves_total = gridDim.x * 4;
    int per = (n + waves_total - 1) / waves_total;
    int i0 = wid * per;
    int i1 = min(n, i0 + per);
    for (int i = i0; i < i1; ++i) {
        const float* xr = xhat + (size_t)i * CIN; // uniform address -> scalar loads
        float a0 = 0.f, a1 = 0.f, a2 = 0.f, a3 = 0.f;
#pragma unroll
        for (int c = 0; c < CIN; c += 4) {
            a0 = fmaf(xr[c + 0], w[c + 0], a0);
            a1 = fmaf(xr[c + 1], w[c + 1], a1);
            a2 = fmaf(xr[c + 2], w[c + 2], a2);
            a3 = fmaf(xr[c + 3], w[c + 3], a3);
        }
        out[(size_t)i * COUT + lane] = (a0 + a1) + (a2 + a3);
    }
}

// Sparse scatter pass for the 26 non-center offsets.
// blockIdx.y -> offset k (center skipped). Each wave: W[k] column in VGPRs,
// loads 64 idx at a time, ballot-compacts, iterates valid bits with uniform
// control flow (lanes = output channels), scatters via HW f32 atomics.
__global__ __launch_bounds__(256) void k_scatter(const float* __restrict__ xhat,
                                                 const float* __restrict__ W,
                                                 const int* __restrict__ nbr,
                                                 float* __restrict__ out, int n) {
    int lane = threadIdx.x;
    int k = blockIdx.y;
    if (k >= KCEN) ++k;                           // skip center offset

    float w[CIN];
#pragma unroll
    for (int c = 0; c < CIN; ++c) w[c] = W[k * (CIN * COUT) + c * COUT + lane];

    const int* nk = nbr + (size_t)k * n;
    int wid = __builtin_amdgcn_readfirstlane(blockIdx.x * 4 + threadIdx.y);
    int waves_total = gridDim.x * 4;
    int nchunks = (n + 63) >> 6;

    for (int ch = wid; ch < nchunks; ch += waves_total) {
        int base = ch * 64;
        int i = base + lane;
        int idx = (i < n) ? nk[i] : -1;
        unsigned long long m = __ballot(idx >= 0);
        while (m) {
            int b = __builtin_ctzll(m);
            m &= (m - 1);
            int src = __builtin_amdgcn_readlane(idx, b);   // uniform (SGPR)
            const float* xr = xhat + (size_t)src * CIN;    // uniform -> scalar loads
            float a0 = 0.f, a1 = 0.f, a2 = 0.f, a3 = 0.f;
#pragma unroll
            for (int c = 0; c < CIN; c += 4) {
                a0 = fmaf(xr[c + 0], w[c + 0], a0);
                a1 = fmaf(xr[c + 1], w[c + 1], a1);
                a2 = fmaf(xr[c + 2], w[c + 2], a2);
                a3 = fmaf(xr[c + 3], w[c + 3], a3);
            }
            unsafeAtomicAdd(&out[(size_t)(base + b) * COUT + lane],
                            (a0 + a1) + (a2 + a3));
        }
    }
}

extern "C" void kernel_launch(void* const* d_in, const int* in_sizes, int n_in,
                              void* d_out, int out_size, void* d_ws, size_t ws_size,
                              hipStream_t stream) {
    const float* feat  = (const float*)d_in[0];
    const float* gamma = (const float*)d_in[1];
    const float* beta  = (const float*)d_in[2];
    const float* W     = (const float*)d_in[3];
    const int*   nbr   = (const int*)d_in[4];
    float* out = (float*)d_out;
    float* ws  = (float*)d_ws;

    int n  = in_sizes[0] / CIN;     // 400000
    int n4 = in_sizes[0] / 4;       // N*32/4 float4 elements
    float* xhat = ws + 128;

    hipLaunchKernelGGL(k_zero, dim3(1), dim3(128), 0, stream, ws);
    hipLaunchKernelGGL(k_reduce, dim3(512), dim3(256), 0, stream, feat, ws, n4);
    hipLaunchKernelGGL(k_final, dim3(1), dim3(32), 0, stream, gamma, beta, ws, 1.0f / (float)n);
    hipLaunchKernelGGL(k_norm, dim3(2048), dim3(256), 0, stream, feat, ws, xhat, n4);
    hipLaunchKernelGGL(k_center, dim3(1024), dim3(64, 4), 0, stream, xhat, W, out, n);
    hipLaunchKernelGGL(k_scatter, dim3(128, 26), dim3(64, 4), 0, stream, xhat, W, nbr, out, n);
}